// Round 7
// baseline (134.165 us; speedup 1.0000x reference)
//
#include <hip/hip_runtime.h>
#include <hip/hip_bf16.h>
#include <math.h>

// DeformConv2D MI355X: b=4,c=64,H=W=128,KS=3,N=9 -> out[b,o,h,w] = sum_{c,n} W[o,c,n]*bilin(xpad,p)
// R7: offset_setup reads MFMA A-frags directly from global (no LDS stage, 1 barrier, LDS 9.7KB);
//     gather_mfma gathers 4 items/iter via 16-lane groups (2x ILP on the L2 latency chain).
//     Numerics bit-identical to R6 (absmax 0.03125).

typedef __attribute__((ext_vector_type(8)))  short short8;
typedef __attribute__((ext_vector_type(4)))  short short4_t;
typedef __attribute__((ext_vector_type(16))) float float16;

#define NPIX 65536
#define XS_STRIDE 580   // xs leading dim (bf16): dword stride 290 = 2 mod 32 -> 2-way (free)

// workspace layout (byte offsets)
#define XPB_B   0u           // bf16 hi padded NHWC x : 8,652,800 B
#define XPL_B   8652800u     // bf16 lo residual      : 8,652,800 B
#define WBB_B   17305600u    // W_conv bf16 MFMA B-frags: 73,728 B
#define WOH_B   17379328u    // W_off hi B-frags      : 36,864 B
#define WOL_B   17416192u    // W_off lo B-frags      : 36,864 B
#define CPK_B   17453056u    // packed corner coords  : 2048*288*4  = 2,359,296 B
#define CWT_B   19812352u    // factor weights float4 : 2048*288*16 = 9,437,184 B (end 29,249,536)

__device__ inline unsigned short f2bf(float f) {
    unsigned int u = __float_as_uint(f);
    u += 0x7fffu + ((u >> 16) & 1u);           // RNE
    return (unsigned short)(u >> 16);
}
__device__ inline float bfhi2f(unsigned int v) { return __uint_as_float(v & 0xffff0000u); }
__device__ inline float bflo2f(unsigned int v) { return __uint_as_float(v << 16); }

// ---------------------------------------------------------------- K1: pad/transpose + weight prep
__global__ __launch_bounds__(1024) void pad_prep(const float* __restrict__ x,
                                                 const float* __restrict__ W_off,
                                                 const float* __restrict__ W_conv,
                                                 char* __restrict__ wsb) {
    unsigned short* xpb = (unsigned short*)(wsb + XPB_B);
    unsigned short* xpl = (unsigned short*)(wsb + XPL_B);
    int t = threadIdx.x;
    if (blockIdx.x >= 520) {   // ---- weight prep: 16 blocks x 3456 items
        unsigned short* Wb  = (unsigned short*)(wsb + WBB_B);
        unsigned short* Woh = (unsigned short*)(wsb + WOH_B);
        unsigned short* Wol = (unsigned short*)(wsb + WOL_B);
        int wb = blockIdx.x - 520;
        for (int ii = t; ii < 3456; ii += 1024) {
            int e = wb * 3456 + ii;
            if (e < 36864) {
                int j = e & 7, lane = (e >> 3) & 63, t2 = e >> 9;
                int ks = t2 % 36, nt = t2 / 36;
                int k = ks * 16 + ((lane >> 5) << 3) + j;
                int n = nt * 32 + (lane & 31);
                Wb[e] = f2bf(W_conv[(n * 64 + (k & 63)) * 9 + (k >> 6)]);
            } else {
                int e2 = e - 36864;     // W_off hi/lo frags, N=32 (18 used)
                int j = e2 & 7, lane = (e2 >> 3) & 63, ksg = e2 >> 9;
                int k = ksg * 16 + ((lane >> 5) << 3) + j;
                int c = k & 63, tap = k >> 6, n = lane & 31;
                float v = 0.f;
                if (n < 18) { int ko = (n < 9) ? 2 * n : 2 * (n - 9) + 1; v = W_off[(ko * 64 + c) * 9 + tap]; }
                unsigned short hi = f2bf(v);
                Woh[e2] = hi;
                Wol[e2] = f2bf(v - bfhi2f((unsigned int)hi << 16));
            }
        }
        return;
    }
    __shared__ float tile[64][129];
    int hp = blockIdx.x % 130, b = blockIdx.x / 130;
    int rowbase = ((b * 130 + hp) * 130) * 64;
    if (hp == 0 || hp == 129) {
        for (int i = t; i < 130 * 32; i += 1024) {
            ((unsigned*)(xpb + rowbase))[i] = 0u;
            ((unsigned*)(xpl + rowbase))[i] = 0u;
        }
        return;
    }
    int h = hp - 1;
    {
        int w = t & 127, cq = t >> 7;
#pragma unroll
        for (int cc = 0; cc < 8; cc++) {
            int c = cq + cc * 8;
            tile[c][w] = x[(((b * 64 + c) * 128) + h) * 128 + w];   // coalesced over w
        }
    }
    __syncthreads();
    {
        int c2 = (t & 31) * 2, wq = t >> 5;
        if (wq == 0) { ((unsigned*)(xpb + rowbase))[t & 31] = 0u; ((unsigned*)(xpl + rowbase))[t & 31] = 0u; }
        if (wq == 1) { ((unsigned*)(xpb + rowbase + 129 * 64))[t & 31] = 0u; ((unsigned*)(xpl + rowbase + 129 * 64))[t & 31] = 0u; }
#pragma unroll
        for (int w = wq; w < 128; w += 32) {
            float v0 = tile[c2][w], v1 = tile[c2 + 1][w];
            unsigned short h0 = f2bf(v0), h1 = f2bf(v1);
            unsigned short l0 = f2bf(v0 - bfhi2f((unsigned int)h0 << 16));
            unsigned short l1 = f2bf(v1 - bfhi2f((unsigned int)h1 << 16));
            int ad = (rowbase + (w + 1) * 64) / 2 + (t & 31);
            ((unsigned*)xpb)[ad] = (unsigned)h0 | ((unsigned)h1 << 16);
            ((unsigned*)xpl)[ad] = (unsigned)l0 | ((unsigned)l1 << 16);
        }
    }
}

// ---------------------------------------------------------------- K2a: offset conv + bilinear setup
// block = 256 thr (4 waves), 32 pixels. A-frags read DIRECTLY from global (L2-hot, 9 independent
// iterations -> deep VMEM pipelining). LDS = obuf 9,728 B only. One barrier.
__global__ __launch_bounds__(256) void offset_setup(const float* __restrict__ b_off,
                                                    char* __restrict__ wsb) {
    const unsigned short* xpb = (const unsigned short*)(wsb + XPB_B);
    const unsigned short* xpl = (const unsigned short*)(wsb + XPL_B);
    const short8* Woh = (const short8*)(wsb + WOH_B);
    const short8* Wol = (const short8*)(wsb + WOL_B);
    unsigned* cpkG = (unsigned*)(wsb + CPK_B);
    float4*   cwtG = (float4*)(wsb + CWT_B);

    __shared__ float obuf[4 * 32 * 19];                      // 9,728 B

    int t = threadIdx.x;
    int lane = t & 63, wv = t >> 6;
    int pixbase = blockIdx.x * 32;
    int w0 = pixbase & 127, h0 = (pixbase >> 7) & 127, bimg = pixbase >> 14;
    int m = lane & 31, half8 = (lane >> 5) << 3;

    // ---- P1: offset conv via split-bf16 MFMA; A-frags straight from global
    float16 acc;
#pragma unroll
    for (int r = 0; r < 16; r++) acc[r] = 0.f;
#pragma unroll
    for (int i = 0; i < 9; i++) {
        int ksg = wv * 9 + i;
        int tap = ksg >> 2;
        int c0 = ((ksg & 3) << 4) + half8;
        int ty = tap / 3, tx = tap - 3 * ty;
        int ga = ((bimg * 130 + h0 + ty) * 130 + (w0 + m + tx)) * 64 + c0;   // elem offset
        short8 ah = *(const short8*)(xpb + ga);              // 16B/lane, L2-hot
        short8 al = *(const short8*)(xpl + ga);
        short8 bh = Woh[ksg * 64 + lane];
        short8 bl = Wol[ksg * 64 + lane];
        acc = __builtin_amdgcn_mfma_f32_32x32x16_bf16(ah, bh, acc, 0, 0, 0);
        acc = __builtin_amdgcn_mfma_f32_32x32x16_bf16(ah, bl, acc, 0, 0, 0);
        acc = __builtin_amdgcn_mfma_f32_32x32x16_bf16(al, bh, acc, 0, 0, 0);
    }
    // ---- P2: partials -> obuf[wv][row][n] (n<18 used, stride 19)
    if (m < 18) {
#pragma unroll
        for (int r = 0; r < 16; r++) {
            int row = (r & 3) + 8 * (r >> 2) + 4 * (lane >> 5);
            obuf[(wv * 32 + row) * 19 + m] = acc[r];
        }
    }
    __syncthreads();

    // ---- P3: per-(pixel,tap) bilinear setup (exact fp32 decisions) -> global cdat
    int gbase = blockIdx.x * 288;
#pragma unroll
    for (int s = 0; s < 2; s++) {
        if (s == 1 && t >= 32) break;
        int it = t + s * 256;
        int p = (it * 7282) >> 16;              // /9
        int n = it - p * 9;
        float orow = b_off[2 * n], ocol = b_off[2 * n + 1];
#pragma unroll
        for (int kq = 0; kq < 4; kq++) {
            orow += obuf[(kq * 32 + p) * 19 + n];
            ocol += obuf[(kq * 32 + p) * 19 + 9 + n];
        }
        float pr = (float)(h0 + (n / 3)) + orow;
        float pc = (float)(w0 + p + (n % 3)) + ocol;
        float flr = floorf(pr), flc = floorf(pc);
        float qlt_r = fminf(fmaxf(flr, 0.f), 129.f);
        float qlt_c = fminf(fmaxf(flc, 0.f), 129.f);
        float qrb_r = fminf(fmaxf(flr + 1.f, 0.f), 129.f);
        float qrb_c = fminf(fmaxf(flc + 1.f, 0.f), 129.f);
        bool mr = (pr < 1.f) || (pr > 128.f);
        bool mc = (pc < 1.f) || (pc > 128.f);
        float pr2 = mr ? flr : pr; pr2 = fminf(fmaxf(pr2, 0.f), 129.f);
        float pc2 = mc ? flc : pc; pc2 = fminf(fmaxf(pc2, 0.f), 129.f);
        float wr_lt = 1.f + (qlt_r - pr2);
        float wr_rb = 1.f - (qrb_r - pr2);
        float wc_lt = 1.f + (qlt_c - pc2);
        float wc_rb = 1.f - (qrb_c - pc2);
        int ilt_r = (int)qlt_r, ilt_c = (int)qlt_c;
        int irb_r = (int)qrb_r, irb_c = (int)qrb_c;
        cpkG[gbase + it] = (unsigned)ilt_r | ((unsigned)ilt_c << 8)
                         | ((unsigned)irb_r << 16) | ((unsigned)irb_c << 24);
        cwtG[gbase + it] = make_float4(wr_lt, wr_rb, wc_lt, wc_rb);
    }
}

// ---------------------------------------------------------------- K2b: gather + contraction MFMA
// block = 256 thr (4 waves), 32 pixels. Gather: 4 items/iter via 16-lane groups (lane: 4 ch,
// uint2 loads) -> 18 iterations, 2x ILP. Then 32x32x16 MFMA + combine + store. LDS 37,120 B.
__global__ __launch_bounds__(256) void gather_mfma(float* __restrict__ out,
                                                   const char* __restrict__ wsb) {
    const short8* Wb = (const short8*)(wsb + WBB_B);
    const unsigned* cpkG = (const unsigned*)(wsb + CPK_B);
    const float4*   cwtG = (const float4*)(wsb + CWT_B);

    __shared__ __attribute__((aligned(16))) char smem[37120];
    unsigned short* xs = (unsigned short*)smem;              // [32][580] bf16
    float* obuf2 = (float*)smem;                             // [2][32][33] = 8,448 B (after B2)

    int t = threadIdx.x;
    int lane = t & 63, wv = t >> 6;
    int pixbase = blockIdx.x * 32;
    int w0 = pixbase & 127, h0 = (pixbase >> 7) & 127, bimg = pixbase >> 14;
    int m = lane & 31, half8 = (lane >> 5) << 3;

    // ---- P5: gather; group g=lane>>4 owns item wv*72 + 4i + g; lane16 = 4 channels (8B)
    {
        int grp = lane >> 4, lane16 = lane & 15;
        int cp8 = lane16 * 8;
        const char* bp = (const char*)(wsb + XPB_B) + (size_t)bimg * (130 * 130 * 128);
        char* xsb = (char*)xs;
        int item = blockIdx.x * 288 + wv * 72 + grp;
        int n5 = grp;                                        // p0 = wv*8, n0 = grp (grp<9)
        int sa = wv * 8 * (XS_STRIDE * 2) + n5 * 128;
#pragma unroll 3
        for (int i = 0; i < 18; i++) {
            unsigned pk = cpkG[item];                        // uniform per 16-lane group
            float4 wt = cwtG[item];
            int rlt = pk & 255, clt = (pk >> 8) & 255, rrb = (pk >> 16) & 255, crb = pk >> 24;
            int aLT = rlt * 16640 + clt * 128;
            int aRB = rrb * 16640 + crb * 128;
            int aLB = rlt * 16640 + crb * 128;
            int aRT = rrb * 16640 + clt * 128;
            float Gx = wt.x * wt.z, Gy = wt.y * wt.w, Gz = wt.x * wt.w, Gw = wt.y * wt.z;
            uint2 vlt = *(const uint2*)(bp + aLT + cp8);
            uint2 vrb = *(const uint2*)(bp + aRB + cp8);
            uint2 vlb = *(const uint2*)(bp + aLB + cp8);
            uint2 vrt = *(const uint2*)(bp + aRT + cp8);
            float s0 = fmaf(Gx, bflo2f(vlt.x), fmaf(Gy, bflo2f(vrb.x), fmaf(Gz, bflo2f(vlb.x), Gw * bflo2f(vrt.x))));
            float s1 = fmaf(Gx, bfhi2f(vlt.x), fmaf(Gy, bfhi2f(vrb.x), fmaf(Gz, bfhi2f(vlb.x), Gw * bfhi2f(vrt.x))));
            float s2 = fmaf(Gx, bflo2f(vlt.y), fmaf(Gy, bflo2f(vrb.y), fmaf(Gz, bflo2f(vlb.y), Gw * bflo2f(vrt.y))));
            float s3 = fmaf(Gx, bfhi2f(vlt.y), fmaf(Gy, bfhi2f(vrb.y), fmaf(Gz, bfhi2f(vlb.y), Gw * bfhi2f(vrt.y))));
            __hip_bfloat162 pk01 = __float22bfloat162_rn(make_float2(s0, s1));
            __hip_bfloat162 pk23 = __float22bfloat162_rn(make_float2(s2, s3));
            uint2 pkv = make_uint2(*(unsigned*)&pk01, *(unsigned*)&pk23);
            *(uint2*)(xsb + sa + cp8) = pkv;
            item += 4; n5 += 4; sa += 512;
            if (n5 >= 9) { n5 -= 9; sa += 8; }   // (p+1, n-9)
        }
    }
    __syncthreads();                                         // B1

    // ---- P6: contraction MFMA. wave: nt = N-tile (32 outs), kh = K-half (288)
    int nt = wv & 1, kh = wv >> 1;
    float16 acc;
#pragma unroll
    for (int r = 0; r < 16; r++) acc[r] = 0.f;
    for (int i2 = 0; i2 < 18; i2++) {
        int ksg = kh * 18 + i2;
        int baseE = m * XS_STRIDE + ksg * 16 + half8;
        short4_t a0 = *(const short4_t*)(xs + baseE);        // b64: stride 290dw -> 2-way only
        short4_t a1 = *(const short4_t*)(xs + baseE + 4);
        short8 af = __builtin_shufflevector(a0, a1, 0, 1, 2, 3, 4, 5, 6, 7);
        short8 bfv = Wb[(nt * 36 + ksg) * 64 + lane];        // coalesced 1KB, L2-resident
        acc = __builtin_amdgcn_mfma_f32_32x32x16_bf16(af, bfv, acc, 0, 0, 0);
    }
    __syncthreads();                                         // B2: all xs reads done
    // ---- P7: K-half combine (obuf2 aliases xs) + coalesced store
    if (kh == 1) {
#pragma unroll
        for (int r = 0; r < 16; r++) {
            int mrow = (r & 3) + 8 * (r >> 2) + 4 * (lane >> 5);
            obuf2[nt * 1056 + mrow * 33 + m] = acc[r];
        }
    }
    __syncthreads();                                         // B3
    if (kh == 0) {
#pragma unroll
        for (int r = 0; r < 16; r++) {
            int mrow = (r & 3) + 8 * (r >> 2) + 4 * (lane >> 5);
            int oi = nt * 1056 + mrow * 33 + m;
            obuf2[oi] = acc[r] + obuf2[oi];
        }
    }
    __syncthreads();                                         // B4
#pragma unroll
    for (int i = 0; i < 8; i++) {
        int lin = i * 256 + t;
        int o = lin >> 5, p = lin & 31;
        float v = obuf2[(o >> 5) * 1056 + p * 33 + (o & 31)];
        out[((bimg * 64 + o) << 14) + (h0 << 7) + w0 + p] = v;
    }
}

// ---------------------------------------------------------------- launch
extern "C" void kernel_launch(void* const* d_in, const int* in_sizes, int n_in,
                              void* d_out, int out_size, void* d_ws, size_t ws_size,
                              hipStream_t stream) {
    const float* x      = (const float*)d_in[0];
    const float* W_off  = (const float*)d_in[1];
    const float* b_off  = (const float*)d_in[2];
    const float* W_conv = (const float*)d_in[3];
    char* wsb  = (char*)d_ws;            // needs 29,249,536 B
    float* out = (float*)d_out;

    hipLaunchKernelGGL(pad_prep, dim3(536), dim3(1024), 0, stream, x, W_off, W_conv, wsb);
    hipLaunchKernelGGL(offset_setup, dim3(NPIX / 32), dim3(256), 0, stream, b_off, wsb);
    hipLaunchKernelGGL(gather_mfma, dim3(NPIX / 32), dim3(256), 0, stream, out, wsb);
}

// Round 8
// 126.171 us; speedup vs baseline: 1.0634x; 1.0634x over previous
//
#include <hip/hip_runtime.h>
#include <hip/hip_bf16.h>
#include <math.h>

// DeformConv2D MI355X: b=4,c=64,H=W=128,KS=3,N=9 -> out[b,o,h,w] = sum_{c,n} W[o,c,n]*bilin(xpad,p)
// R8: revert R7's regressions (staged offset_setup, half-wave gather = R6 structure);
//     gather_mfma K-half combine: disjoint obuf2 regions + single barrier (was 2 barriers + RMW).
//     Numerics bit-identical (absmax 0.03125).

typedef __attribute__((ext_vector_type(8)))  short short8;
typedef __attribute__((ext_vector_type(4)))  short short4_t;
typedef __attribute__((ext_vector_type(16))) float float16;

#define NPIX 65536
#define XS_STRIDE 580   // xs leading dim (bf16): dword stride 290 = 2 mod 32 -> 2-way (free)
#define K2_WS 68        // stage wp stride (64ch + 4 pad)
#define K2_RS 2312      // stage row stride (34*68)

// workspace layout (byte offsets)
#define XPB_B   0u           // bf16 hi padded NHWC x : 8,652,800 B
#define XPL_B   8652800u     // bf16 lo residual      : 8,652,800 B
#define WBB_B   17305600u    // W_conv bf16 MFMA B-frags: 73,728 B
#define WOH_B   17379328u    // W_off hi B-frags      : 36,864 B
#define WOL_B   17416192u    // W_off lo B-frags      : 36,864 B
#define CPK_B   17453056u    // packed corner coords  : 2048*288*4  = 2,359,296 B
#define CWT_B   19812352u    // factor weights float4 : 2048*288*16 = 9,437,184 B (end 29,249,536)

__device__ inline unsigned short f2bf(float f) {
    unsigned int u = __float_as_uint(f);
    u += 0x7fffu + ((u >> 16) & 1u);           // RNE
    return (unsigned short)(u >> 16);
}
__device__ inline float bfhi2f(unsigned int v) { return __uint_as_float(v & 0xffff0000u); }
__device__ inline float bflo2f(unsigned int v) { return __uint_as_float(v << 16); }

// ---------------------------------------------------------------- K1: pad/transpose + weight prep
__global__ __launch_bounds__(1024) void pad_prep(const float* __restrict__ x,
                                                 const float* __restrict__ W_off,
                                                 const float* __restrict__ W_conv,
                                                 char* __restrict__ wsb) {
    unsigned short* xpb = (unsigned short*)(wsb + XPB_B);
    unsigned short* xpl = (unsigned short*)(wsb + XPL_B);
    int t = threadIdx.x;
    if (blockIdx.x >= 520) {   // ---- weight prep: 16 blocks x 3456 items
        unsigned short* Wb  = (unsigned short*)(wsb + WBB_B);
        unsigned short* Woh = (unsigned short*)(wsb + WOH_B);
        unsigned short* Wol = (unsigned short*)(wsb + WOL_B);
        int wb = blockIdx.x - 520;
        for (int ii = t; ii < 3456; ii += 1024) {
            int e = wb * 3456 + ii;
            if (e < 36864) {
                int j = e & 7, lane = (e >> 3) & 63, t2 = e >> 9;
                int ks = t2 % 36, nt = t2 / 36;
                int k = ks * 16 + ((lane >> 5) << 3) + j;
                int n = nt * 32 + (lane & 31);
                Wb[e] = f2bf(W_conv[(n * 64 + (k & 63)) * 9 + (k >> 6)]);
            } else {
                int e2 = e - 36864;     // W_off hi/lo frags, N=32 (18 used)
                int j = e2 & 7, lane = (e2 >> 3) & 63, ksg = e2 >> 9;
                int k = ksg * 16 + ((lane >> 5) << 3) + j;
                int c = k & 63, tap = k >> 6, n = lane & 31;
                float v = 0.f;
                if (n < 18) { int ko = (n < 9) ? 2 * n : 2 * (n - 9) + 1; v = W_off[(ko * 64 + c) * 9 + tap]; }
                unsigned short hi = f2bf(v);
                Woh[e2] = hi;
                Wol[e2] = f2bf(v - bfhi2f((unsigned int)hi << 16));
            }
        }
        return;
    }
    __shared__ float tile[64][129];
    int hp = blockIdx.x % 130, b = blockIdx.x / 130;
    int rowbase = ((b * 130 + hp) * 130) * 64;
    if (hp == 0 || hp == 129) {
        for (int i = t; i < 130 * 32; i += 1024) {
            ((unsigned*)(xpb + rowbase))[i] = 0u;
            ((unsigned*)(xpl + rowbase))[i] = 0u;
        }
        return;
    }
    int h = hp - 1;
    {
        int w = t & 127, cq = t >> 7;
#pragma unroll
        for (int cc = 0; cc < 8; cc++) {
            int c = cq + cc * 8;
            tile[c][w] = x[(((b * 64 + c) * 128) + h) * 128 + w];   // coalesced over w
        }
    }
    __syncthreads();
    {
        int c2 = (t & 31) * 2, wq = t >> 5;
        if (wq == 0) { ((unsigned*)(xpb + rowbase))[t & 31] = 0u; ((unsigned*)(xpl + rowbase))[t & 31] = 0u; }
        if (wq == 1) { ((unsigned*)(xpb + rowbase + 129 * 64))[t & 31] = 0u; ((unsigned*)(xpl + rowbase + 129 * 64))[t & 31] = 0u; }
#pragma unroll
        for (int w = wq; w < 128; w += 32) {
            float v0 = tile[c2][w], v1 = tile[c2 + 1][w];
            unsigned short h0 = f2bf(v0), h1 = f2bf(v1);
            unsigned short l0 = f2bf(v0 - bfhi2f((unsigned int)h0 << 16));
            unsigned short l1 = f2bf(v1 - bfhi2f((unsigned int)h1 << 16));
            int ad = (rowbase + (w + 1) * 64) / 2 + (t & 31);
            ((unsigned*)xpb)[ad] = (unsigned)h0 | ((unsigned)h1 << 16);
            ((unsigned*)xpl)[ad] = (unsigned)l0 | ((unsigned)l1 << 16);
        }
    }
}

// ---------------------------------------------------------------- K2a: offset conv + bilinear setup
// block = 256 thr (4 waves), 32 pixels. Stage 3x34x64 hi/lo (coalesced) -> 27 split-bf16 MFMA ->
// obuf (aliases stage) -> per-item packed corners + factor weights to GLOBAL. LDS 27,744 B.
__global__ __launch_bounds__(256) void offset_setup(const float* __restrict__ b_off,
                                                    char* __restrict__ wsb) {
    const unsigned* xpbw = (const unsigned*)(wsb + XPB_B);
    const unsigned* xplw = (const unsigned*)(wsb + XPL_B);
    const short8* Woh = (const short8*)(wsb + WOH_B);
    const short8* Wol = (const short8*)(wsb + WOL_B);
    unsigned* cpkG = (unsigned*)(wsb + CPK_B);
    float4*   cwtG = (float4*)(wsb + CWT_B);

    __shared__ __attribute__((aligned(16))) char smem[27744];
    unsigned short* xh = (unsigned short*)smem;              // stage hi: 3*2312 (13,872 B)
    unsigned short* xl = xh + 3 * K2_RS;                     // stage lo
    float* obuf = (float*)smem;                              // [4][32][19] = 9,728 B (after B2)

    int t = threadIdx.x;
    int lane = t & 63, wv = t >> 6;
    int pixbase = blockIdx.x * 32;
    int w0 = pixbase & 127, h0 = (pixbase >> 7) & 127, bimg = pixbase >> 14;

    // ---- P0: stage 3 rows x 34 cols x 64 ch hi/lo (dword = 2ch), fully coalesced
    for (int i = t; i < 3264; i += 256) {
        int row = i / 1088, rem = i - row * 1088;
        int wp = rem >> 5, cd = rem & 31;
        int g = ((bimg * 130 + h0 + row) * 130 + (w0 + wp)) * 32 + cd;
        int d = row * (K2_RS / 2) + wp * (K2_WS / 2) + cd;
        ((unsigned*)xh)[d] = xpbw[g];
        ((unsigned*)xl)[d] = xplw[g];
    }
    __syncthreads();                                         // B1

    // ---- P1: offset conv via split-bf16 MFMA (M=32 px, N=32 (18 used), K=576/4 per wave)
    int m = lane & 31, half8 = (lane >> 5) << 3;
    float16 acc;
#pragma unroll
    for (int r = 0; r < 16; r++) acc[r] = 0.f;
#pragma unroll
    for (int i = 0; i < 9; i++) {
        int ksg = wv * 9 + i;
        int tap = ksg >> 2;
        int c0 = ((ksg & 3) << 4) + half8;
        int ty = tap / 3, tx = tap - 3 * ty;
        int eb = ty * K2_RS + (m + tx) * K2_WS + c0;
        short4_t h0v = *(const short4_t*)(xh + eb);
        short4_t h1v = *(const short4_t*)(xh + eb + 4);
        short4_t l0v = *(const short4_t*)(xl + eb);
        short4_t l1v = *(const short4_t*)(xl + eb + 4);
        short8 ah = __builtin_shufflevector(h0v, h1v, 0, 1, 2, 3, 4, 5, 6, 7);
        short8 al = __builtin_shufflevector(l0v, l1v, 0, 1, 2, 3, 4, 5, 6, 7);
        short8 bh = Woh[ksg * 64 + lane];
        short8 bl = Wol[ksg * 64 + lane];
        acc = __builtin_amdgcn_mfma_f32_32x32x16_bf16(ah, bh, acc, 0, 0, 0);
        acc = __builtin_amdgcn_mfma_f32_32x32x16_bf16(ah, bl, acc, 0, 0, 0);
        acc = __builtin_amdgcn_mfma_f32_32x32x16_bf16(al, bh, acc, 0, 0, 0);
    }
    __syncthreads();                                         // B2: stage reads done, obuf fresh
    // ---- P2: partials -> obuf[wv][row][n] (n<18 used, stride 19)
    if (m < 18) {
#pragma unroll
        for (int r = 0; r < 16; r++) {
            int row = (r & 3) + 8 * (r >> 2) + 4 * (lane >> 5);
            obuf[(wv * 32 + row) * 19 + m] = acc[r];
        }
    }
    __syncthreads();                                         // B3

    // ---- P3: per-(pixel,tap) bilinear setup (exact fp32 decisions) -> global cdat
    int gbase = blockIdx.x * 288;
#pragma unroll
    for (int s = 0; s < 2; s++) {
        if (s == 1 && t >= 32) break;
        int it = t + s * 256;
        int p = (it * 7282) >> 16;              // /9
        int n = it - p * 9;
        float orow = b_off[2 * n], ocol = b_off[2 * n + 1];
#pragma unroll
        for (int kq = 0; kq < 4; kq++) {
            orow += obuf[(kq * 32 + p) * 19 + n];
            ocol += obuf[(kq * 32 + p) * 19 + 9 + n];
        }
        float pr = (float)(h0 + (n / 3)) + orow;
        float pc = (float)(w0 + p + (n % 3)) + ocol;
        float flr = floorf(pr), flc = floorf(pc);
        float qlt_r = fminf(fmaxf(flr, 0.f), 129.f);
        float qlt_c = fminf(fmaxf(flc, 0.f), 129.f);
        float qrb_r = fminf(fmaxf(flr + 1.f, 0.f), 129.f);
        float qrb_c = fminf(fmaxf(flc + 1.f, 0.f), 129.f);
        bool mr = (pr < 1.f) || (pr > 128.f);
        bool mc = (pc < 1.f) || (pc > 128.f);
        float pr2 = mr ? flr : pr; pr2 = fminf(fmaxf(pr2, 0.f), 129.f);
        float pc2 = mc ? flc : pc; pc2 = fminf(fmaxf(pc2, 0.f), 129.f);
        float wr_lt = 1.f + (qlt_r - pr2);
        float wr_rb = 1.f - (qrb_r - pr2);
        float wc_lt = 1.f + (qlt_c - pc2);
        float wc_rb = 1.f - (qrb_c - pc2);
        int ilt_r = (int)qlt_r, ilt_c = (int)qlt_c;
        int irb_r = (int)qrb_r, irb_c = (int)qrb_c;
        cpkG[gbase + it] = (unsigned)ilt_r | ((unsigned)ilt_c << 8)
                         | ((unsigned)irb_r << 16) | ((unsigned)irb_c << 24);
        cwtG[gbase + it] = make_float4(wr_lt, wr_rb, wc_lt, wc_rb);
    }
}

// ---------------------------------------------------------------- K2b: gather + contraction MFMA
// block = 256 thr (4 waves), 32 pixels. P5 gather -> xs LDS. P6 MFMA (nt x kh).
// P7: both K-halves write disjoint obuf2 regions, ONE barrier, add at store. LDS 37,120 B.
__global__ __launch_bounds__(256) void gather_mfma(float* __restrict__ out,
                                                   const char* __restrict__ wsb) {
    const short8* Wb = (const short8*)(wsb + WBB_B);
    const unsigned* cpkG = (const unsigned*)(wsb + CPK_B);
    const float4*   cwtG = (const float4*)(wsb + CWT_B);

    __shared__ __attribute__((aligned(16))) char smem[37120];
    unsigned short* xs = (unsigned short*)smem;              // [32][580] bf16
    float* obuf2 = (float*)smem;                             // [4][32][33] = 16,896 B (after B2)

    int t = threadIdx.x;
    int lane = t & 63, wv = t >> 6;
    int pixbase = blockIdx.x * 32;
    int w0 = pixbase & 127, h0 = (pixbase >> 7) & 127, bimg = pixbase >> 14;
    int m = lane & 31, half8 = (lane >> 5) << 3;

    // ---- P5: gather (2 items/wave-load, half-wave per item; 128B coalesced corner rows)
    {
        int half = lane >> 5;
        int cp4 = (lane & 31) * 4;
        const char* bp = (const char*)(wsb + XPB_B) + (size_t)bimg * (130 * 130 * 128);
        char* xsb = (char*)xs;
        int base = blockIdx.x * 288 + wv * 72;
        int n5 = half;
        int sa = wv * 8 * (XS_STRIDE * 2) + n5 * 128;
#pragma unroll 4
        for (int i = 0; i < 36; i++) {
            int item = base + 2 * i + half;
            unsigned pk = cpkG[item];                        // uniform per half-wave, L2-hot
            float4 wt = cwtG[item];
            int rlt = pk & 255, clt = (pk >> 8) & 255, rrb = (pk >> 16) & 255, crb = pk >> 24;
            int aLT = rlt * 16640 + clt * 128;
            int aRB = rrb * 16640 + crb * 128;
            int aLB = rlt * 16640 + crb * 128;
            int aRT = rrb * 16640 + clt * 128;
            float Gx = wt.x * wt.z, Gy = wt.y * wt.w, Gz = wt.x * wt.w, Gw = wt.y * wt.z;
            unsigned int vlt = *(const unsigned int*)(bp + aLT + cp4);
            unsigned int vrb = *(const unsigned int*)(bp + aRB + cp4);
            unsigned int vlb = *(const unsigned int*)(bp + aLB + cp4);
            unsigned int vrt = *(const unsigned int*)(bp + aRT + cp4);
            float lo = fmaf(Gx, bflo2f(vlt), fmaf(Gy, bflo2f(vrb), fmaf(Gz, bflo2f(vlb), Gw * bflo2f(vrt))));
            float hi = fmaf(Gx, bfhi2f(vlt), fmaf(Gy, bfhi2f(vrb), fmaf(Gz, bfhi2f(vlb), Gw * bfhi2f(vrt))));
            __hip_bfloat162 pk2 = __float22bfloat162_rn(make_float2(lo, hi));
            *(unsigned int*)(xsb + sa + cp4) = *(unsigned int*)&pk2;
            n5 += 2; sa += 256;
            if (n5 >= 9) { n5 -= 9; sa += 8; }   // (p+1, n-9)
        }
    }
    __syncthreads();                                         // B1

    // ---- P6: contraction MFMA. wave: nt = N-tile (32 outs), kh = K-half (288)
    int nt = wv & 1, kh = wv >> 1;
    float16 acc;
#pragma unroll
    for (int r = 0; r < 16; r++) acc[r] = 0.f;
    for (int i2 = 0; i2 < 18; i2++) {
        int ksg = kh * 18 + i2;
        int baseE = m * XS_STRIDE + ksg * 16 + half8;
        short4_t a0 = *(const short4_t*)(xs + baseE);        // b64: stride 290dw -> 2-way only
        short4_t a1 = *(const short4_t*)(xs + baseE + 4);
        short8 af = __builtin_shufflevector(a0, a1, 0, 1, 2, 3, 4, 5, 6, 7);
        short8 bfv = Wb[(nt * 36 + ksg) * 64 + lane];        // coalesced 1KB, L2-resident
        acc = __builtin_amdgcn_mfma_f32_32x32x16_bf16(af, bfv, acc, 0, 0, 0);
    }
    __syncthreads();                                         // B2: all xs reads done -> obuf2 alias safe
    // ---- P7: each (kh,nt) wave writes its own obuf2 region; single barrier; add at store
#pragma unroll
    for (int r = 0; r < 16; r++) {
        int mrow = (r & 3) + 8 * (r >> 2) + 4 * (lane >> 5);
        obuf2[(kh * 2 + nt) * 1056 + mrow * 33 + m] = acc[r];
    }
    __syncthreads();                                         // B3
#pragma unroll
    for (int i = 0; i < 8; i++) {
        int lin = i * 256 + t;
        int o = lin >> 5, p = lin & 31;
        int oi = (o >> 5) * 1056 + p * 33 + (o & 31);
        float v = obuf2[oi] + obuf2[oi + 2112];   // acc_kh0 + acc_kh1 (same order as R6)
        out[((bimg * 64 + o) << 14) + (h0 << 7) + w0 + p] = v;
    }
}

// ---------------------------------------------------------------- launch
extern "C" void kernel_launch(void* const* d_in, const int* in_sizes, int n_in,
                              void* d_out, int out_size, void* d_ws, size_t ws_size,
                              hipStream_t stream) {
    const float* x      = (const float*)d_in[0];
    const float* W_off  = (const float*)d_in[1];
    const float* b_off  = (const float*)d_in[2];
    const float* W_conv = (const float*)d_in[3];
    char* wsb  = (char*)d_ws;            // needs 29,249,536 B
    float* out = (float*)d_out;

    hipLaunchKernelGGL(pad_prep, dim3(536), dim3(1024), 0, stream, x, W_off, W_conv, wsb);
    hipLaunchKernelGGL(offset_setup, dim3(NPIX / 32), dim3(256), 0, stream, b_off, wsb);
    hipLaunchKernelGGL(gather_mfma, dim3(NPIX / 32), dim3(256), 0, stream, out, wsb);
}